// Round 10
// baseline (617.666 us; speedup 1.0000x reference)
//
#include <hip/hip_runtime.h>

#define Bn 4
#define Nn 50000
#define En 1000000
#define FOUT 8

typedef unsigned int u32;
typedef unsigned short u16;
typedef __attribute__((ext_vector_type(8))) short bf16x8;
typedef __attribute__((ext_vector_type(4))) float f32x4;
typedef __attribute__((ext_vector_type(4))) int i32x4;

// ---- ws layout (bytes) ----
#define BLOB_BYTES 24576
#define W1T_OFF 0       // [64 q][32 k] bf16 (k padded 20->32)
#define W2T_OFF 4096    // [64 q][64 k] bf16
#define W3T_OFF 12288   // [64 c][64 k] bf16
#define B1_OFF 20480    // f32[64] sigma-permuted
#define B2_OFF 20736
#define B3_OFF 20992
#define BSUM_OFF 21248  // u32[256] in blob slack

#define CNT_OFF    24576
#define ROWPTR_OFF 224576
#define FILL_OFF   424704
#define PAIRS_OFF  624768                        // u32[En]: src | dst<<16  (Nn < 2^16)
#define MSG_OFF    4624768                       // bf16[En*8]
#define WS_NEEDED (MSG_OFF + (size_t)En * FOUT * 2)   // 20,624,768 B (round-6 proven)

__device__ __forceinline__ float fast_tanh(float x) {
    float e = __builtin_amdgcn_exp2f(x * 2.8853900817779268f);
    return 1.0f - 2.0f * __builtin_amdgcn_rcpf(e + 1.0f);
}
__device__ __forceinline__ u32 pkbf(float lo, float hi) {
    u32 r;
    asm("v_cvt_pk_bf16_f32 %0, %1, %2" : "=v"(r) : "v"(lo), "v"(hi));
    return r;
}
__device__ __forceinline__ float bflo(u32 u) { return __builtin_bit_cast(float, u << 16); }
__device__ __forceinline__ float bfhi(u32 u) { return __builtin_bit_cast(float, u & 0xffff0000u); }
__device__ __forceinline__ float bfu(u16 v) { return __builtin_bit_cast(float, (u32)v << 16); }
__device__ __forceinline__ u16 f2bf(float x) {
    u32 u = __builtin_bit_cast(u32, x);
    return (u16)((u + 0x7fff + ((u >> 16) & 1)) >> 16);
}
// sigma-permutation of MLP hidden channels (HW-verified rounds 4-9)
__device__ __forceinline__ int PERM_Q(int q) {
    int mi = q >> 4, g = (q >> 2) & 3, r = q & 3;
    return ((mi >> 1) << 5) | (g << 3) | ((mi & 1) << 2) | r;
}

__global__ void gno_init_weights(const float* __restrict__ W1, const float* __restrict__ b1,
                                 const float* __restrict__ W2, const float* __restrict__ b2,
                                 const float* __restrict__ W3, const float* __restrict__ b3,
                                 unsigned char* __restrict__ blob)
{
    int idx = blockIdx.x * 256 + threadIdx.x;
    if (idx < 2048) {
        int q = idx >> 5, k = idx & 31;
        float v = (k < 20) ? W1[k * 64 + PERM_Q(q)] : 0.0f;
        *(u16*)(blob + W1T_OFF + q * 64 + 2 * k) = f2bf(v);
    } else if (idx < 6144) {
        int j = idx - 2048, q = j >> 6, k = j & 63;
        *(u16*)(blob + W2T_OFF + q * 128 + 2 * k) = f2bf(W2[k * 64 + PERM_Q(q)]);
    } else if (idx < 10240) {
        int j = idx - 6144, c = j >> 6, k = j & 63;
        *(u16*)(blob + W3T_OFF + c * 128 + 2 * k) = f2bf(W3[k * 64 + c]);
    } else if (idx < 10304) { int q = idx - 10240; *(float*)(blob + B1_OFF + q * 4) = b1[PERM_Q(q)]; }
    else if (idx < 10368)   { int q = idx - 10304; *(float*)(blob + B2_OFF + q * 4) = b2[PERM_Q(q)]; }
    else if (idx < 10432)   { int c = idx - 10368; *(float*)(blob + B3_OFF + c * 4) = b3[c]; }
}

// ---- CSR build ----
__global__ void gno_hist(const int* __restrict__ neigh, u32* __restrict__ cnt) {
    const int e = blockIdx.x * 256 + threadIdx.x;
    if (e < En) atomicAdd(&cnt[neigh[e]], 1u);
}
__global__ __launch_bounds__(256) void gno_scan1(const u32* __restrict__ cnt,
                                                 u32* __restrict__ rowptr,
                                                 u32* __restrict__ bsum)
{
    __shared__ u32 wtot[4];
    const int tid = threadIdx.x, lane = tid & 63, w = tid >> 6;
    const int n = blockIdx.x * 256 + tid;
    const u32 c = (n < Nn) ? cnt[n] : 0u;
    u32 inc = c;
    #pragma unroll
    for (int off = 1; off < 64; off <<= 1) {
        u32 x = __shfl_up(inc, off, 64);
        if (lane >= off) inc += x;
    }
    if (lane == 63) wtot[w] = inc;
    __syncthreads();
    u32 woff = 0;
    for (int i = 0; i < w; ++i) woff += wtot[i];
    if (n < Nn) rowptr[n] = woff + inc - c;
    if (tid == 255) bsum[blockIdx.x] = woff + inc;
}
__global__ __launch_bounds__(256) void gno_scan2(u32* __restrict__ bsum, const int nb)
{
    __shared__ u32 wtot[4];
    const int tid = threadIdx.x, lane = tid & 63, w = tid >> 6;
    const u32 c = (tid < nb) ? bsum[tid] : 0u;
    u32 inc = c;
    #pragma unroll
    for (int off = 1; off < 64; off <<= 1) {
        u32 x = __shfl_up(inc, off, 64);
        if (lane >= off) inc += x;
    }
    if (lane == 63) wtot[w] = inc;
    __syncthreads();
    u32 woff = 0;
    for (int i = 0; i < w; ++i) woff += wtot[i];
    if (tid < nb) bsum[tid] = woff + inc - c;
}
__global__ __launch_bounds__(256) void gno_scan3(u32* __restrict__ rowptr,
                                                 const u32* __restrict__ bsum,
                                                 u32* __restrict__ fill)
{
    const int n = blockIdx.x * 256 + threadIdx.x;
    if (n < Nn) {
        const u32 v = rowptr[n] + bsum[blockIdx.x];
        rowptr[n] = v;
        fill[n] = v;
    }
    if (n == 0) rowptr[Nn] = En;
}
__global__ void gno_slot(const int* __restrict__ neigh, u32* __restrict__ fill,
                         u32* __restrict__ pairs) {
    const int e = blockIdx.x * 256 + threadIdx.x;
    if (e < En) {
        const int dn = neigh[e];
        const int sn = neigh[En + e];
        const u32 s = atomicAdd(&fill[dn], 1u);
        pairs[s] = (u32)sn | ((u32)dn << 16);
    }
}

// ---- edge MLP over CSR slot order: 4 waves x 32 slots per block ----
// Round 9 proved spill-free at 48 VGPR / WRITE==msg. Round 10: lift the
// occupancy cap 4->8 waves/EU (VGPR budget 64 >= 48; LDS 10KB*8 = 80KB/CU ok).
__global__ __launch_bounds__(256, 8) void gno_edge_mfma(
    const float* __restrict__ batch, const float* __restrict__ points,
    const u32* __restrict__ pairs, const unsigned char* __restrict__ wblob,
    const int b, u16* __restrict__ msg)
{
    __shared__ __align__(128) unsigned char feat_lds[4 * 32 * 64];  // [w][e<32][32 bf16]
    __shared__ __align__(16) unsigned char by_lds[4 * 32 * 16];     // [w][e<32][8 bf16]

    const int tid = threadIdx.x;
    const int lane = tid & 63;
    const int w = tid >> 6;
    const int s0 = (blockIdx.x * 4 + w) * 32;
    if (s0 >= En) return;                  // wave-uniform; no barriers anywhere
    const int t = lane & 15;
    const int g = lane >> 4;

    // stage feat: lanes 0-31, one edge each (wave-private region, in-wave ordering)
    if (lane < 32) {
        const u32 p = pairs[s0 + lane];
        const int sn = (int)(p & 0xffffu);
        const int dn = (int)(p >> 16);
        const float2 ps = *(const float2*)(points + 2 * (size_t)sn);
        const float2 pd = *(const float2*)(points + 2 * (size_t)dn);
        const float4* bxp = (const float4*)(batch + ((size_t)b * Nn + sn) * 8);
        const float4 bx0 = bxp[0], bx1 = bxp[1];
        const float4* byp = (const float4*)(batch + ((size_t)b * Nn + dn) * 8);
        const float4 by0 = byp[0], by1 = byp[1];
        unsigned char* fb = feat_lds + w * 2048;
        const int base = lane << 6;
        const int sw = (lane & 7) << 4;
        *(uint4*)(fb + ((base + 0)  ^ sw)) = make_uint4(pkbf(ps.x, ps.y), pkbf(pd.x, pd.y),
                                                        pkbf(bx0.x, bx0.y), pkbf(bx0.z, bx0.w));
        *(uint4*)(fb + ((base + 16) ^ sw)) = make_uint4(pkbf(bx1.x, bx1.y), pkbf(bx1.z, bx1.w),
                                                        pkbf(by0.x, by0.y), pkbf(by0.z, by0.w));
        *(uint4*)(fb + ((base + 32) ^ sw)) = make_uint4(pkbf(by1.x, by1.y), pkbf(by1.z, by1.w), 0u, 0u);
        *(uint4*)(fb + ((base + 48) ^ sw)) = make_uint4(0u, 0u, 0u, 0u);
        *(uint4*)(by_lds + w * 512 + lane * 16) = make_uint4(pkbf(by0.x, by0.y), pkbf(by0.z, by0.w),
                                                             pkbf(by1.x, by1.y), pkbf(by1.z, by1.w));
    }

    f32x4 acc[4][2], acc2[4][2];
    bf16x8 afr[4], bfr[2];
    u32 pk[4][2][2];

    // L1 (K=32): weights direct from global (L1/L2-hot, identical across blocks)
    #pragma unroll
    for (int mi = 0; mi < 4; ++mi) {
        const f32x4 bv = *(const f32x4*)(wblob + B1_OFF + (mi * 16 + g * 4) * 4);
        #pragma unroll
        for (int ni = 0; ni < 2; ++ni) acc[mi][ni] = bv;
    }
    #pragma unroll
    for (int mi = 0; mi < 4; ++mi)
        afr[mi] = *(const bf16x8*)(wblob + W1T_OFF + (mi * 16 + t) * 64 + (g << 4));
    #pragma unroll
    for (int nj = 0; nj < 2; ++nj) {
        const int row = nj * 16 + t;
        bfr[nj] = *(const bf16x8*)(feat_lds + w * 2048 + ((row * 64 + (g << 4)) ^ ((row & 7) << 4)));
    }
    #pragma unroll
    for (int mi = 0; mi < 4; ++mi)
        #pragma unroll
        for (int nj = 0; nj < 2; ++nj)
            acc[mi][nj] = __builtin_amdgcn_mfma_f32_16x16x32_bf16(afr[mi], bfr[nj], acc[mi][nj], 0, 0, 0);

    #pragma unroll
    for (int mi = 0; mi < 4; ++mi)
        #pragma unroll
        for (int ni = 0; ni < 2; ++ni) {
            pk[mi][ni][0] = pkbf(fast_tanh(acc[mi][ni][0]), fast_tanh(acc[mi][ni][1]));
            pk[mi][ni][1] = pkbf(fast_tanh(acc[mi][ni][2]), fast_tanh(acc[mi][ni][3]));
        }

    // L2 (K=64): B-fragments straight from pk registers (sigma handoff)
    #pragma unroll
    for (int mi = 0; mi < 4; ++mi) {
        const f32x4 bv = *(const f32x4*)(wblob + B2_OFF + (mi * 16 + g * 4) * 4);
        #pragma unroll
        for (int ni = 0; ni < 2; ++ni) acc2[mi][ni] = bv;
    }
    #pragma unroll
    for (int kt = 0; kt < 2; ++kt) {
        #pragma unroll
        for (int mi = 0; mi < 4; ++mi)
            afr[mi] = *(const bf16x8*)(wblob + W2T_OFF + (mi * 16 + t) * 128 + kt * 64 + (g << 4));
        #pragma unroll
        for (int nj = 0; nj < 2; ++nj) {
            const i32x4 bi = { (int)pk[2 * kt][nj][0], (int)pk[2 * kt][nj][1],
                               (int)pk[2 * kt + 1][nj][0], (int)pk[2 * kt + 1][nj][1] };
            const bf16x8 bf = __builtin_bit_cast(bf16x8, bi);
            #pragma unroll
            for (int mi = 0; mi < 4; ++mi)
                acc2[mi][nj] = __builtin_amdgcn_mfma_f32_16x16x32_bf16(afr[mi], bf, acc2[mi][nj], 0, 0, 0);
        }
    }
    #pragma unroll
    for (int mi = 0; mi < 4; ++mi)
        #pragma unroll
        for (int ni = 0; ni < 2; ++ni) {
            pk[mi][ni][0] = pkbf(fast_tanh(acc2[mi][ni][0]), fast_tanh(acc2[mi][ni][1]));
            pk[mi][ni][1] = pkbf(fast_tanh(acc2[mi][ni][2]), fast_tanh(acc2[mi][ni][3]));
        }

    // L3 (K=64): mats cols natural c = 16*mi + 4*g + r
    #pragma unroll
    for (int mi = 0; mi < 4; ++mi) {
        const f32x4 bv = *(const f32x4*)(wblob + B3_OFF + (mi * 16 + g * 4) * 4);
        #pragma unroll
        for (int ni = 0; ni < 2; ++ni) acc[mi][ni] = bv;
    }
    #pragma unroll
    for (int kt = 0; kt < 2; ++kt) {
        #pragma unroll
        for (int mi = 0; mi < 4; ++mi)
            afr[mi] = *(const bf16x8*)(wblob + W3T_OFF + (mi * 16 + t) * 128 + kt * 64 + (g << 4));
        #pragma unroll
        for (int nj = 0; nj < 2; ++nj) {
            const i32x4 bi = { (int)pk[2 * kt][nj][0], (int)pk[2 * kt][nj][1],
                               (int)pk[2 * kt + 1][nj][0], (int)pk[2 * kt + 1][nj][1] };
            const bf16x8 bf = __builtin_bit_cast(bf16x8, bi);
            #pragma unroll
            for (int mi = 0; mi < 4; ++mi)
                acc[mi][nj] = __builtin_amdgcn_mfma_f32_16x16x32_bf16(afr[mi], bf, acc[mi][nj], 0, 0, 0);
        }
    }

    // epilogue: msg[s][i] = sum_j mats[i][j]*by[j]; slot-contiguous coalesced store
    const int jhalf = g & 1;
    #pragma unroll
    for (int ni = 0; ni < 2; ++ni) {
        const int el = ni * 16 + t;
        const uint2 byw = *(const uint2*)(by_lds + w * 512 + el * 16 + jhalf * 8);
        const float f0 = bflo(byw.x), f1 = bfhi(byw.x), f2 = bflo(byw.y), f3 = bfhi(byw.y);
        u32 pks[4];
        #pragma unroll
        for (int mi = 0; mi < 4; ++mi) {
            const f32x4 a = acc[mi][ni];
            float p = fmaf(a[0], f0, fmaf(a[1], f1, fmaf(a[2], f2, a[3] * f3)));
            const float m  = p + __shfl_xor(p, 16, 64);   // full dot, i = 2mi+(lane>>5)
            const float mo = __shfl_xor(m, 32, 64);       // partner channel
            pks[mi] = pkbf(m, mo);                        // (2mi, 2mi+1) valid on g==0
        }
        if (g == 0)
            *(uint4*)(msg + (size_t)(s0 + el) * 8) = make_uint4(pks[0], pks[1], pks[2], pks[3]);
    }
}

// ---- fused CSR gather + finalize: 8 lanes per node ----
__global__ __launch_bounds__(256) void gno_gather_out(
    const float* __restrict__ batch, const float* __restrict__ Wlin,
    const u16* __restrict__ msg, const u32* __restrict__ rowptr,
    const u32* __restrict__ cnt, float* __restrict__ out, const int b)
{
    const int tid = threadIdx.x;
    const int n = blockIdx.x * 32 + (tid >> 3);
    const int c = tid & 7;
    if (n >= Nn) return;
    const u32 dg = cnt[n];
    const u32 j0 = rowptr[n];
    float acc = 0.0f;
    for (u32 j = j0; j < j0 + dg; ++j) acc += bfu(msg[(size_t)j * 8 + c]);
    float v = acc * __builtin_amdgcn_rcpf((float)dg + 1.0f);
    const float* br = batch + ((size_t)b * Nn + n) * 8;
    #pragma unroll
    for (int j = 0; j < 8; ++j) v = fmaf(br[j], Wlin[j * FOUT + c], v);
    out[((size_t)b * Nn + n) * 8 + c] = v;   // coalesced
}

extern "C" void kernel_launch(void* const* d_in, const int* in_sizes, int n_in,
                              void* d_out, int out_size, void* d_ws, size_t ws_size,
                              hipStream_t stream) {
    const float* batch  = (const float*)d_in[0];
    const float* points = (const float*)d_in[1];
    const int*   neigh  = (const int*)d_in[2];
    const float* W1     = (const float*)d_in[3];
    const float* b1     = (const float*)d_in[4];
    const float* W2     = (const float*)d_in[5];
    const float* b2     = (const float*)d_in[6];
    const float* W3     = (const float*)d_in[7];
    const float* b3     = (const float*)d_in[8];
    const float* Wlin   = (const float*)d_in[9];
    float* out = (float*)d_out;

    unsigned char* ws = (unsigned char*)d_ws;
    u32* cnt    = (u32*)(ws + CNT_OFF);
    u32* rowptr = (u32*)(ws + ROWPTR_OFF);
    u32* fill   = (u32*)(ws + FILL_OFF);
    u32* bsum   = (u32*)(ws + BSUM_OFF);
    u32* pairs  = (u32*)(ws + PAIRS_OFF);
    u16* msg    = (u16*)(ws + MSG_OFF);
    if (ws_size < WS_NEEDED) return;

    const dim3 b256(256);
    const dim3 gE((En + 255) / 256);
    const dim3 gEdge((En / 32 + 3) / 4);     // 7813 blocks, 4 waves x 32 slots
    const dim3 gN((Nn + 255) / 256);         // 196 (<= 256 for scan2)
    const dim3 gGather((Nn + 31) / 32);

    hipMemsetAsync(cnt, 0, Nn * sizeof(u32), stream);
    gno_init_weights<<<dim3(41), b256, 0, stream>>>(W1, b1, W2, b2, W3, b3, ws);
    gno_hist<<<gE, b256, 0, stream>>>(neigh, cnt);
    gno_scan1<<<gN, b256, 0, stream>>>(cnt, rowptr, bsum);
    gno_scan2<<<dim3(1), b256, 0, stream>>>(bsum, (int)gN.x);
    gno_scan3<<<gN, b256, 0, stream>>>(rowptr, bsum, fill);
    gno_slot<<<gE, b256, 0, stream>>>(neigh, fill, pairs);
    for (int b = 0; b < Bn; ++b) {
        gno_edge_mfma<<<gEdge, b256, 0, stream>>>(batch, points, pairs, ws, b, msg);
        gno_gather_out<<<gGather, b256, 0, stream>>>(batch, Wlin, msg, rowptr, cnt, out, b);
    }
}

// Round 11
// 378.914 us; speedup vs baseline: 1.6301x; 1.6301x over previous
//
#include <hip/hip_runtime.h>

#define Bn 4
#define Nn 50000
#define En 1000000
#define FOUT 8

typedef unsigned int u32;
typedef unsigned short u16;
typedef __attribute__((ext_vector_type(8))) short bf16x8;
typedef __attribute__((ext_vector_type(4))) float f32x4;
typedef __attribute__((ext_vector_type(4))) int i32x4;

// ---- ws layout (bytes) ----
#define BLOB_BYTES 24576
#define W1T_OFF 0       // [64 q][32 k] bf16 (k padded 20->32)
#define W2T_OFF 4096    // [64 q][64 k] bf16
#define W3T_OFF 12288   // [64 c][64 k] bf16
#define B1_OFF 20480    // f32[64] sigma-permuted
#define B2_OFF 20736
#define B3_OFF 20992
#define BSUM_OFF 21248  // u32[256] in blob slack

#define CNT_OFF    24576
#define ROWPTR_OFF 224576
#define FILL_OFF   424704
#define PAIRS_OFF  624768                        // u32[En]: src | dst<<16  (Nn < 2^16)
#define MSG_OFF    4624768                       // bf16[En*8]
#define WS_NEEDED (MSG_OFF + (size_t)En * FOUT * 2)   // 20,624,768 B (round-6 proven)

__device__ __forceinline__ float fast_tanh(float x) {
    float e = __builtin_amdgcn_exp2f(x * 2.8853900817779268f);
    return 1.0f - 2.0f * __builtin_amdgcn_rcpf(e + 1.0f);
}
__device__ __forceinline__ u32 pkbf(float lo, float hi) {
    u32 r;
    asm("v_cvt_pk_bf16_f32 %0, %1, %2" : "=v"(r) : "v"(lo), "v"(hi));
    return r;
}
__device__ __forceinline__ float bflo(u32 u) { return __builtin_bit_cast(float, u << 16); }
__device__ __forceinline__ float bfhi(u32 u) { return __builtin_bit_cast(float, u & 0xffff0000u); }
__device__ __forceinline__ float bfu(u16 v) { return __builtin_bit_cast(float, (u32)v << 16); }
__device__ __forceinline__ u16 f2bf(float x) {
    u32 u = __builtin_bit_cast(u32, x);
    return (u16)((u + 0x7fff + ((u >> 16) & 1)) >> 16);
}
// sigma-permutation of MLP hidden channels (HW-verified rounds 4-10)
__device__ __forceinline__ int PERM_Q(int q) {
    int mi = q >> 4, g = (q >> 2) & 3, r = q & 3;
    return ((mi >> 1) << 5) | (g << 3) | ((mi & 1) << 2) | r;
}

__global__ void gno_init_weights(const float* __restrict__ W1, const float* __restrict__ b1,
                                 const float* __restrict__ W2, const float* __restrict__ b2,
                                 const float* __restrict__ W3, const float* __restrict__ b3,
                                 unsigned char* __restrict__ blob)
{
    int idx = blockIdx.x * 256 + threadIdx.x;
    if (idx < 2048) {
        int q = idx >> 5, k = idx & 31;
        float v = (k < 20) ? W1[k * 64 + PERM_Q(q)] : 0.0f;
        *(u16*)(blob + W1T_OFF + q * 64 + 2 * k) = f2bf(v);
    } else if (idx < 6144) {
        int j = idx - 2048, q = j >> 6, k = j & 63;
        *(u16*)(blob + W2T_OFF + q * 128 + 2 * k) = f2bf(W2[k * 64 + PERM_Q(q)]);
    } else if (idx < 10240) {
        int j = idx - 6144, c = j >> 6, k = j & 63;
        *(u16*)(blob + W3T_OFF + c * 128 + 2 * k) = f2bf(W3[k * 64 + c]);
    } else if (idx < 10304) { int q = idx - 10240; *(float*)(blob + B1_OFF + q * 4) = b1[PERM_Q(q)]; }
    else if (idx < 10368)   { int q = idx - 10304; *(float*)(blob + B2_OFF + q * 4) = b2[PERM_Q(q)]; }
    else if (idx < 10432)   { int c = idx - 10368; *(float*)(blob + B3_OFF + c * 4) = b3[c]; }
}

// ---- CSR build ----
__global__ void gno_hist(const int* __restrict__ neigh, u32* __restrict__ cnt) {
    const int e = blockIdx.x * 256 + threadIdx.x;
    if (e < En) atomicAdd(&cnt[neigh[e]], 1u);
}
__global__ __launch_bounds__(256) void gno_scan1(const u32* __restrict__ cnt,
                                                 u32* __restrict__ rowptr,
                                                 u32* __restrict__ bsum)
{
    __shared__ u32 wtot[4];
    const int tid = threadIdx.x, lane = tid & 63, w = tid >> 6;
    const int n = blockIdx.x * 256 + tid;
    const u32 c = (n < Nn) ? cnt[n] : 0u;
    u32 inc = c;
    #pragma unroll
    for (int off = 1; off < 64; off <<= 1) {
        u32 x = __shfl_up(inc, off, 64);
        if (lane >= off) inc += x;
    }
    if (lane == 63) wtot[w] = inc;
    __syncthreads();
    u32 woff = 0;
    for (int i = 0; i < w; ++i) woff += wtot[i];
    if (n < Nn) rowptr[n] = woff + inc - c;
    if (tid == 255) bsum[blockIdx.x] = woff + inc;
}
__global__ __launch_bounds__(256) void gno_scan2(u32* __restrict__ bsum, const int nb)
{
    __shared__ u32 wtot[4];
    const int tid = threadIdx.x, lane = tid & 63, w = tid >> 6;
    const u32 c = (tid < nb) ? bsum[tid] : 0u;
    u32 inc = c;
    #pragma unroll
    for (int off = 1; off < 64; off <<= 1) {
        u32 x = __shfl_up(inc, off, 64);
        if (lane >= off) inc += x;
    }
    if (lane == 63) wtot[w] = inc;
    __syncthreads();
    u32 woff = 0;
    for (int i = 0; i < w; ++i) woff += wtot[i];
    if (tid < nb) bsum[tid] = woff + inc - c;
}
__global__ __launch_bounds__(256) void gno_scan3(u32* __restrict__ rowptr,
                                                 const u32* __restrict__ bsum,
                                                 u32* __restrict__ fill)
{
    const int n = blockIdx.x * 256 + threadIdx.x;
    if (n < Nn) {
        const u32 v = rowptr[n] + bsum[blockIdx.x];
        rowptr[n] = v;
        fill[n] = v;
    }
    if (n == 0) rowptr[Nn] = En;
}
__global__ void gno_slot(const int* __restrict__ neigh, u32* __restrict__ fill,
                         u32* __restrict__ pairs) {
    const int e = blockIdx.x * 256 + threadIdx.x;
    if (e < En) {
        const int dn = neigh[e];
        const int sn = neigh[En + e];
        const u32 s = atomicAdd(&fill[dn], 1u);
        pairs[s] = (u32)sn | ((u32)dn << 16);
    }
}

// ---- edge MLP over CSR slot order: 4 waves x 64 slots per block ----
// 64 edges/wave (halves stall events per edge vs round 9) with each layer's
// M processed in two 32-channel halves to stay under the 128-reg occupancy
// quantum at __launch_bounds__(256,4):
//   peak live ~ pk_prev(32) + acc_half(2x4 f32x4 = 32) + pk_cur(16) + afr(8) < 128.
// Sigma handoff unchanged: L1/L2 half h produces pk rows mi=2h,2h+1 == K-block kt=h.
__global__ __launch_bounds__(256, 4) void gno_edge_mfma(
    const float* __restrict__ batch, const float* __restrict__ points,
    const u32* __restrict__ pairs, const unsigned char* __restrict__ wblob,
    const int b, u16* __restrict__ msg)
{
    __shared__ __align__(128) unsigned char feat_lds[4 * 64 * 64];  // [w][e][32 bf16]
    __shared__ __align__(16) unsigned char by_lds[4 * 64 * 16];     // [w][e][8 bf16]

    const int tid = threadIdx.x;
    const int lane = tid & 63;
    const int w = tid >> 6;
    const int s0 = (blockIdx.x * 4 + w) * 64;
    if (s0 >= En) return;                  // wave-uniform tail guard; no barriers
    const int t = lane & 15;
    const int g = lane >> 4;

    // stage feat: all 64 lanes, one slot each (wave-private region, in-wave ordering)
    {
        const u32 p = pairs[s0 + lane];
        const int sn = (int)(p & 0xffffu);
        const int dn = (int)(p >> 16);
        const float2 ps = *(const float2*)(points + 2 * (size_t)sn);
        const float2 pd = *(const float2*)(points + 2 * (size_t)dn);
        const float4* bxp = (const float4*)(batch + ((size_t)b * Nn + sn) * 8);
        const float4 bx0 = bxp[0], bx1 = bxp[1];
        const float4* byp = (const float4*)(batch + ((size_t)b * Nn + dn) * 8);
        const float4 by0 = byp[0], by1 = byp[1];
        unsigned char* fb = feat_lds + w * 4096;
        const int base = lane << 6;
        const int sw = (lane & 7) << 4;
        *(uint4*)(fb + ((base + 0)  ^ sw)) = make_uint4(pkbf(ps.x, ps.y), pkbf(pd.x, pd.y),
                                                        pkbf(bx0.x, bx0.y), pkbf(bx0.z, bx0.w));
        *(uint4*)(fb + ((base + 16) ^ sw)) = make_uint4(pkbf(bx1.x, bx1.y), pkbf(bx1.z, bx1.w),
                                                        pkbf(by0.x, by0.y), pkbf(by0.z, by0.w));
        *(uint4*)(fb + ((base + 32) ^ sw)) = make_uint4(pkbf(by1.x, by1.y), pkbf(by1.z, by1.w), 0u, 0u);
        *(uint4*)(fb + ((base + 48) ^ sw)) = make_uint4(0u, 0u, 0u, 0u);
        *(uint4*)(by_lds + w * 1024 + lane * 16) = make_uint4(pkbf(by0.x, by0.y), pkbf(by0.z, by0.w),
                                                              pkbf(by1.x, by1.y), pkbf(by1.z, by1.w));
    }

    u32 pk1[4][4][2];   // L1 outputs, packed bf16 (sigma: lane-held == lane-needed)

    // ----- L1 (K=32), M in two halves -----
    {
        bf16x8 bfr[4];
        #pragma unroll
        for (int nj = 0; nj < 4; ++nj) {
            const int row = nj * 16 + t;
            bfr[nj] = *(const bf16x8*)(feat_lds + w * 4096 + ((row * 64 + (g << 4)) ^ ((row & 7) << 4)));
        }
        #pragma unroll
        for (int h = 0; h < 2; ++h) {
            f32x4 acc[2][4];
            bf16x8 afr[2];
            #pragma unroll
            for (int d = 0; d < 2; ++d) {
                const int mi = 2 * h + d;
                const f32x4 bv = *(const f32x4*)(wblob + B1_OFF + (mi * 16 + g * 4) * 4);
                #pragma unroll
                for (int nj = 0; nj < 4; ++nj) acc[d][nj] = bv;
                afr[d] = *(const bf16x8*)(wblob + W1T_OFF + (mi * 16 + t) * 64 + (g << 4));
            }
            #pragma unroll
            for (int d = 0; d < 2; ++d)
                #pragma unroll
                for (int nj = 0; nj < 4; ++nj)
                    acc[d][nj] = __builtin_amdgcn_mfma_f32_16x16x32_bf16(afr[d], bfr[nj], acc[d][nj], 0, 0, 0);
            #pragma unroll
            for (int d = 0; d < 2; ++d)
                #pragma unroll
                for (int nj = 0; nj < 4; ++nj) {
                    pk1[2 * h + d][nj][0] = pkbf(fast_tanh(acc[d][nj][0]), fast_tanh(acc[d][nj][1]));
                    pk1[2 * h + d][nj][1] = pkbf(fast_tanh(acc[d][nj][2]), fast_tanh(acc[d][nj][3]));
                }
        }
    }

    // ----- L2 (K=64), M in two halves; B-frags from pk1 registers -----
    u32 pk2[4][4][2];
    #pragma unroll
    for (int h = 0; h < 2; ++h) {
        f32x4 acc[2][4];
        #pragma unroll
        for (int d = 0; d < 2; ++d) {
            const int mi = 2 * h + d;
            const f32x4 bv = *(const f32x4*)(wblob + B2_OFF + (mi * 16 + g * 4) * 4);
            #pragma unroll
            for (int nj = 0; nj < 4; ++nj) acc[d][nj] = bv;
        }
        #pragma unroll
        for (int kt = 0; kt < 2; ++kt) {
            bf16x8 afr[2];
            #pragma unroll
            for (int d = 0; d < 2; ++d)
                afr[d] = *(const bf16x8*)(wblob + W2T_OFF + ((2 * h + d) * 16 + t) * 128 + kt * 64 + (g << 4));
            #pragma unroll
            for (int nj = 0; nj < 4; ++nj) {
                const i32x4 bi = { (int)pk1[2 * kt][nj][0], (int)pk1[2 * kt][nj][1],
                                   (int)pk1[2 * kt + 1][nj][0], (int)pk1[2 * kt + 1][nj][1] };
                const bf16x8 bf = __builtin_bit_cast(bf16x8, bi);
                #pragma unroll
                for (int d = 0; d < 2; ++d)
                    acc[d][nj] = __builtin_amdgcn_mfma_f32_16x16x32_bf16(afr[d], bf, acc[d][nj], 0, 0, 0);
            }
        }
        #pragma unroll
        for (int d = 0; d < 2; ++d)
            #pragma unroll
            for (int nj = 0; nj < 4; ++nj) {
                pk2[2 * h + d][nj][0] = pkbf(fast_tanh(acc[d][nj][0]), fast_tanh(acc[d][nj][1]));
                pk2[2 * h + d][nj][1] = pkbf(fast_tanh(acc[d][nj][2]), fast_tanh(acc[d][nj][3]));
            }
    }

    // ----- L3 (K=64) + fused epilogue, M in two halves -----
    // half h covers mats cols c = 16*(2h+d)+4g+r -> output channels 4h..4h+3.
    const int jhalf = g & 1;
    #pragma unroll
    for (int h = 0; h < 2; ++h) {
        f32x4 acc[2][4];
        #pragma unroll
        for (int d = 0; d < 2; ++d) {
            const int mi = 2 * h + d;
            const f32x4 bv = *(const f32x4*)(wblob + B3_OFF + (mi * 16 + g * 4) * 4);
            #pragma unroll
            for (int nj = 0; nj < 4; ++nj) acc[d][nj] = bv;
        }
        #pragma unroll
        for (int kt = 0; kt < 2; ++kt) {
            bf16x8 afr[2];
            #pragma unroll
            for (int d = 0; d < 2; ++d)
                afr[d] = *(const bf16x8*)(wblob + W3T_OFF + ((2 * h + d) * 16 + t) * 128 + kt * 64 + (g << 4));
            #pragma unroll
            for (int nj = 0; nj < 4; ++nj) {
                const i32x4 bi = { (int)pk2[2 * kt][nj][0], (int)pk2[2 * kt][nj][1],
                                   (int)pk2[2 * kt + 1][nj][0], (int)pk2[2 * kt + 1][nj][1] };
                const bf16x8 bf = __builtin_bit_cast(bf16x8, bi);
                #pragma unroll
                for (int d = 0; d < 2; ++d)
                    acc[d][nj] = __builtin_amdgcn_mfma_f32_16x16x32_bf16(afr[d], bf, acc[d][nj], 0, 0, 0);
            }
        }
        // epilogue for channels 4h..4h+3: i = 2*(2h+d)+(g>>1), j = jhalf*4+r
        #pragma unroll
        for (int nj = 0; nj < 4; ++nj) {
            const int el = nj * 16 + t;
            const uint2 byw = *(const uint2*)(by_lds + w * 1024 + el * 16 + jhalf * 8);
            const float f0 = bflo(byw.x), f1 = bfhi(byw.x), f2 = bflo(byw.y), f3 = bfhi(byw.y);
            u32 pks[2];
            #pragma unroll
            for (int d = 0; d < 2; ++d) {
                const f32x4 a = acc[d][nj];
                float p = fmaf(a[0], f0, fmaf(a[1], f1, fmaf(a[2], f2, a[3] * f3)));
                const float m  = p + __shfl_xor(p, 16, 64);   // full dot
                const float mo = __shfl_xor(m, 32, 64);       // partner channel
                pks[d] = pkbf(m, mo);                          // (2mi, 2mi+1) on g==0
            }
            if (g == 0)
                *(uint2*)(msg + (size_t)(s0 + el) * 8 + h * 4) = make_uint2(pks[0], pks[1]);
        }
    }
}

// ---- fused CSR gather + finalize: 8 lanes per node ----
__global__ __launch_bounds__(256) void gno_gather_out(
    const float* __restrict__ batch, const float* __restrict__ Wlin,
    const u16* __restrict__ msg, const u32* __restrict__ rowptr,
    const u32* __restrict__ cnt, float* __restrict__ out, const int b)
{
    const int tid = threadIdx.x;
    const int n = blockIdx.x * 32 + (tid >> 3);
    const int c = tid & 7;
    if (n >= Nn) return;
    const u32 dg = cnt[n];
    const u32 j0 = rowptr[n];
    float acc = 0.0f;
    for (u32 j = j0; j < j0 + dg; ++j) acc += bfu(msg[(size_t)j * 8 + c]);
    float v = acc * __builtin_amdgcn_rcpf((float)dg + 1.0f);
    const float* br = batch + ((size_t)b * Nn + n) * 8;
    #pragma unroll
    for (int j = 0; j < 8; ++j) v = fmaf(br[j], Wlin[j * FOUT + c], v);
    out[((size_t)b * Nn + n) * 8 + c] = v;   // coalesced
}

extern "C" void kernel_launch(void* const* d_in, const int* in_sizes, int n_in,
                              void* d_out, int out_size, void* d_ws, size_t ws_size,
                              hipStream_t stream) {
    const float* batch  = (const float*)d_in[0];
    const float* points = (const float*)d_in[1];
    const int*   neigh  = (const int*)d_in[2];
    const float* W1     = (const float*)d_in[3];
    const float* b1     = (const float*)d_in[4];
    const float* W2     = (const float*)d_in[5];
    const float* b2     = (const float*)d_in[6];
    const float* W3     = (const float*)d_in[7];
    const float* b3     = (const float*)d_in[8];
    const float* Wlin   = (const float*)d_in[9];
    float* out = (float*)d_out;

    unsigned char* ws = (unsigned char*)d_ws;
    u32* cnt    = (u32*)(ws + CNT_OFF);
    u32* rowptr = (u32*)(ws + ROWPTR_OFF);
    u32* fill   = (u32*)(ws + FILL_OFF);
    u32* bsum   = (u32*)(ws + BSUM_OFF);
    u32* pairs  = (u32*)(ws + PAIRS_OFF);
    u16* msg    = (u16*)(ws + MSG_OFF);
    if (ws_size < WS_NEEDED) return;

    const dim3 b256(256);
    const dim3 gE((En + 255) / 256);
    const dim3 gEdge((En / 64 + 3) / 4);     // 3907 blocks, 4 waves x 64 slots
    const dim3 gN((Nn + 255) / 256);         // 196 (<= 256 for scan2)
    const dim3 gGather((Nn + 31) / 32);

    hipMemsetAsync(cnt, 0, Nn * sizeof(u32), stream);
    gno_init_weights<<<dim3(41), b256, 0, stream>>>(W1, b1, W2, b2, W3, b3, ws);
    gno_hist<<<gE, b256, 0, stream>>>(neigh, cnt);
    gno_scan1<<<gN, b256, 0, stream>>>(cnt, rowptr, bsum);
    gno_scan2<<<dim3(1), b256, 0, stream>>>(bsum, (int)gN.x);
    gno_scan3<<<gN, b256, 0, stream>>>(rowptr, bsum, fill);
    gno_slot<<<gE, b256, 0, stream>>>(neigh, fill, pairs);
    for (int b = 0; b < Bn; ++b) {
        gno_edge_mfma<<<gEdge, b256, 0, stream>>>(batch, points, pairs, ws, b, msg);
        gno_gather_out<<<gGather, b256, 0, stream>>>(batch, Wlin, msg, rowptr, cnt, out, b);
    }
}